// Round 3
// baseline (1039.401 us; speedup 1.0000x reference)
//
#include <hip/hip_runtime.h>
#include <hip/hip_bf16.h>

typedef int v4i __attribute__((ext_vector_type(4)));

#define GLOBAL_AS(p) ((const __attribute__((address_space(1))) void*)(p))
#define LDS_AS(p)    ((__attribute__((address_space(3))) void*)(p))

#define BM 128
#define BN 128
#define BK 64

// ---------------------------------------------------------------------------
// Kernel 1: static quantize x fp32 -> int8  (x/s, clip, round-half-even)
// ---------------------------------------------------------------------------
__global__ __launch_bounds__(256) void quant_kernel(
    const float* __restrict__ x, signed char* __restrict__ xq,
    const float* __restrict__ iscale, int n4)
{
    int idx = blockIdx.x * 256 + threadIdx.x;
    if (idx >= n4) return;
    float s = iscale[0];
    float4 v = ((const float4*)x)[idx];
    // IEEE division to match numpy exactly; clip then round (RNE) like the ref
    int b0 = (int)rintf(fminf(fmaxf(v.x / s, -128.f), 127.f));
    int b1 = (int)rintf(fminf(fmaxf(v.y / s, -128.f), 127.f));
    int b2 = (int)rintf(fminf(fmaxf(v.z / s, -128.f), 127.f));
    int b3 = (int)rintf(fminf(fmaxf(v.w / s, -128.f), 127.f));
    unsigned packed = (unsigned)(b0 & 255) | ((unsigned)(b1 & 255) << 8) |
                      ((unsigned)(b2 & 255) << 16) | ((unsigned)(b3 & 255) << 24);
    ((unsigned*)xq)[idx] = packed;
}

// ---------------------------------------------------------------------------
// Kernel 2: transpose qweight [K,N] -> [N,K] int8.
// NOTE: harness delivers integer inputs as int32 — one int32 PER int8 value.
// Read int4 (4 values), pack low bytes, LDS 64x64 tile transpose.
// ---------------------------------------------------------------------------
__global__ __launch_bounds__(256) void transpose_kernel(
    const int* __restrict__ in, signed char* __restrict__ out,
    int K, int N)
{
    __shared__ unsigned char t[64][68];   // +4 pad breaks bank aliasing
    const int n0 = blockIdx.x * 64;
    const int k0 = blockIdx.y * 64;
    const int tid = threadIdx.x;

#pragma unroll
    for (int i = 0; i < 4; i++) {
        int d = tid + i * 256;            // 0..1023
        int r = d >> 4, c = d & 15;       // row (k), col group of 4 values (n)
        int4 v = *(const int4*)(in + (size_t)(k0 + r) * N + n0 + c * 4);
        unsigned o = (unsigned)(v.x & 255) | ((unsigned)(v.y & 255) << 8) |
                     ((unsigned)(v.z & 255) << 16) | ((unsigned)(v.w & 255) << 24);
        *(unsigned*)&t[r][c * 4] = o;
    }
    __syncthreads();
#pragma unroll
    for (int i = 0; i < 4; i++) {
        int d = tid + i * 256;
        int n = d >> 4, b = d & 15;       // out row (n), dword col (k)
        unsigned o = (unsigned)t[4 * b + 0][n]
                   | ((unsigned)t[4 * b + 1][n] << 8)
                   | ((unsigned)t[4 * b + 2][n] << 16)
                   | ((unsigned)t[4 * b + 3][n] << 24);
        *(unsigned*)(out + (size_t)(n0 + n) * K + k0 + b * 4) = o;
    }
}

// ---------------------------------------------------------------------------
// Kernel 3: int8 GEMM, m97-analog structure (global_load_lds width-16 staging
// — validated bit-identical to register staging in rounds 1/2).
//   A  = x_int8  [M,K] row-major (K-contiguous)
//   Bt = qweight^T [N,K] row-major (K-contiguous)
//   out[m][n] = (sum_k A[m][k]*Bt[n][k]) * iscale * wscale[n]
// 128x128 block tile, BK=64, 4 waves each computing 64x64 via 4x4 frags of
// mfma_i32_16x16x64_i8.
// ---------------------------------------------------------------------------
__global__ __launch_bounds__(256) void gemm_i8_kernel(
    const signed char* __restrict__ A,
    const signed char* __restrict__ Bt,
    float* __restrict__ out,
    const float* __restrict__ wscale,
    const float* __restrict__ iscale,
    int M, int N, int K)
{
    __shared__ __align__(16) signed char lA[BM * BK];  // [m][k], 64B rows
    __shared__ __align__(16) signed char lB[BN * BK];  // [n][k], 64B rows

    const int tid  = threadIdx.x;
    const int wave = tid >> 6;
    const int lane = tid & 63;
    const int bm = blockIdx.x;
    const int bn = blockIdx.y;

    // ---- staging: wave w stages chunks 2w,2w+1 (each 16 rows x 64B = 1 KiB).
    // LDS dest is wave-uniform base + lane*16; source row = chunk*16 + lane/4,
    // byte col (lane%4)*16.
    const int c0 = wave * 2;
    const signed char* gA0 = A  + (size_t)(bm * BM + c0 * 16 + (lane >> 2)) * K + (lane & 3) * 16;
    const signed char* gA1 = gA0 + (size_t)16 * K;
    const signed char* gB0 = Bt + (size_t)(bn * BN + c0 * 16 + (lane >> 2)) * K + (lane & 3) * 16;
    const signed char* gB1 = gB0 + (size_t)16 * K;
    void* ldsA0 = (void*)&lA[c0 * 1024];
    void* ldsA1 = (void*)&lA[c0 * 1024 + 1024];
    void* ldsB0 = (void*)&lB[c0 * 1024];
    void* ldsB1 = (void*)&lB[c0 * 1024 + 1024];

    // ---- compute addressing -------------------------------------------------
    const int wm = (wave >> 1) * 64;   // wave's m offset in block tile
    const int wn = (wave & 1) * 64;    // wave's n offset
    const int row16 = lane & 15;
    const int quad  = lane >> 4;
    const int aoff = (wm + row16) * 64 + quad * 16;
    const int boff = (wn + row16) * 64 + quad * 16;

    v4i acc[4][4] = {};

    for (int k0 = 0; k0 < K; k0 += BK) {
        __syncthreads();   // previous iter's ds_reads done before overwrite
        __builtin_amdgcn_global_load_lds(GLOBAL_AS(gA0), LDS_AS(ldsA0), 16, 0, 0);
        __builtin_amdgcn_global_load_lds(GLOBAL_AS(gA1), LDS_AS(ldsA1), 16, 0, 0);
        __builtin_amdgcn_global_load_lds(GLOBAL_AS(gB0), LDS_AS(ldsB0), 16, 0, 0);
        __builtin_amdgcn_global_load_lds(GLOBAL_AS(gB1), LDS_AS(ldsB1), 16, 0, 0);
        gA0 += BK; gA1 += BK; gB0 += BK; gB1 += BK;
        __syncthreads();   // drains vmcnt(0): staged data visible

        v4i af[4], bf[4];
#pragma unroll
        for (int mi = 0; mi < 4; mi++)
            af[mi] = *(const v4i*)&lA[aoff + mi * 1024];   // mi*16 rows * 64B
#pragma unroll
        for (int ni = 0; ni < 4; ni++)
            bf[ni] = *(const v4i*)&lB[boff + ni * 1024];
#pragma unroll
        for (int mi = 0; mi < 4; mi++)
#pragma unroll
            for (int ni = 0; ni < 4; ni++)
                acc[mi][ni] = __builtin_amdgcn_mfma_i32_16x16x64_i8(
                    af[mi], bf[ni], acc[mi][ni], 0, 0, 0);
    }

    // ---- epilogue: dequant + store -----------------------------------------
    // C/D layout (16x16): col = lane&15, row = quad*4 + reg   [m89, dtype-indep]
    const float isc = iscale[0];
#pragma unroll
    for (int ni = 0; ni < 4; ni++) {
        const int ncol = bn * BN + wn + ni * 16 + row16;
        const float sc = isc * wscale[ncol];
        float* obase = out + (size_t)(bm * BM + wm + quad * 4) * N + ncol;
#pragma unroll
        for (int mi = 0; mi < 4; mi++) {
#pragma unroll
            for (int r = 0; r < 4; r++) {
                obase[(size_t)(mi * 16 + r) * N] = (float)acc[mi][ni][r] * sc;
            }
        }
    }
}

// ---------------------------------------------------------------------------
extern "C" void kernel_launch(void* const* d_in, const int* in_sizes, int n_in,
                              void* d_out, int out_size, void* d_ws, size_t ws_size,
                              hipStream_t stream) {
    const float* x      = (const float*)d_in[0];
    const int*   qw     = (const int*)d_in[1];      // int8 values, int32 storage
    const float* wscale = (const float*)d_in[2];
    const float* iscale = (const float*)d_in[3];
    float*       out    = (float*)d_out;

    const int N = in_sizes[2];            // 11008
    const int K = in_sizes[1] / N;        // 4096
    const int M = in_sizes[0] / K;        // 8192

    signed char* xq  = (signed char*)d_ws;                     // [M,K]  33.5 MB
    signed char* qwT = (signed char*)d_ws + (size_t)M * K;     // [N,K]  45.1 MB

    // 1) quantize activations
    {
        int n4 = (M * K) / 4;
        quant_kernel<<<(n4 + 255) / 256, 256, 0, stream>>>(x, xq, iscale, n4);
    }
    // 2) transpose weights to K-contiguous int8
    {
        dim3 grid(N / 64, K / 64);
        transpose_kernel<<<grid, 256, 0, stream>>>(qw, qwT, K, N);
    }
    // 3) int8 GEMM + fused dequant
    {
        dim3 grid(M / BM, N / BN);
        gemm_i8_kernel<<<grid, 256, 0, stream>>>(xq, qwT, out, wscale, iscale, M, N, K);
    }
}